// Round 3
// baseline (1622.431 us; speedup 1.0000x reference)
//
#include <hip/hip_runtime.h>
#include <math.h>

#define B_SZ    16384
#define D_EMB   64
#define NTAB    26
#define NROWS   200000

typedef unsigned short ushort_t;
typedef short short8 __attribute__((ext_vector_type(8)));
typedef float f32x4 __attribute__((ext_vector_type(4)));

// bf16 round-to-nearest-even via bit ops
__device__ __forceinline__ ushort_t f2bf(float f) {
    unsigned u = __float_as_uint(f);
    return (ushort_t)((u + 0x7FFFu + ((u >> 16) & 1u)) >> 16);
}
__device__ __forceinline__ float bf2f(ushort_t h) {
    return __uint_as_float((unsigned)h << 16);
}

// async global->LDS, 16B per lane; LDS dest = wave-uniform base + lane*16
#define GLD16(g, l)                                                         \
    __builtin_amdgcn_global_load_lds(                                       \
        (const __attribute__((address_space(1))) void*)(g),                 \
        (__attribute__((address_space(3))) void*)(l), 16, 0, 0)

// ---------------------------------------------------------------------------
// Split all four MFMA-consumed weight matrices to bf16 hi/lo (zero-padded K).
// Ranges: bW1 [256,512] | bW2 [64,256] | tW0 [512,415->416] | tW1 [256,512]
__global__ __launch_bounds__(256)
void conv_weights(const float* __restrict__ bW1, const float* __restrict__ bW2,
                  const float* __restrict__ tW0, const float* __restrict__ tW1,
                  ushort_t* w1h, ushort_t* w1l, ushort_t* w2h, ushort_t* w2l,
                  ushort_t* t0h, ushort_t* t0l, ushort_t* t1h, ushort_t* t1l) {
    int idx = blockIdx.x * 256 + threadIdx.x;          // < 491520
    const float* W; ushort_t *H, *L; int K, Kpad, off;
    if (idx < 131072)        { W = bW1; H = w1h; L = w1l; K = 512; Kpad = 512; off = idx; }
    else if (idx < 147456)   { W = bW2; H = w2h; L = w2l; K = 256; Kpad = 256; off = idx - 131072; }
    else if (idx < 360448)   { W = tW0; H = t0h; L = t0l; K = 415; Kpad = 416; off = idx - 147456; }
    else                     { W = tW1; H = t1h; L = t1l; K = 512; Kpad = 512; off = idx - 360448; }
    int m = off / Kpad, k = off - m * Kpad;
    float v = (k < K) ? W[(long)m * K + k] : 0.f;
    ushort_t h = f2bf(v);
    H[off] = h;
    L[off] = f2bf(v - bf2f(h));
}

// ---------------------------------------------------------------------------
// Bottom layer 0: x1 = relu(X[B,13] @ W[512,13]^T + b), split-written bf16 hi/lo
__global__ __launch_bounds__(256)
void bot0_kernel(const float* __restrict__ X, const float* __restrict__ W,
                 const float* __restrict__ bias,
                 ushort_t* __restrict__ Yh, ushort_t* __restrict__ Yl) {
    int idx = blockIdx.x * 256 + threadIdx.x;   // over B*512
    int b = idx >> 9;
    int m = idx & 511;
    const float* xr = X + (long)b * 13;
    const float* wr = W + (long)m * 13;
    float acc = bias[m];
#pragma unroll
    for (int k = 0; k < 13; ++k) acc = fmaf(xr[k], wr[k], acc);
    float v = fmaxf(acc, 0.f);
    ushort_t h = f2bf(v);
    Yh[idx] = h;
    Yl[idx] = f2bf(v - bf2f(h));
}

// ---------------------------------------------------------------------------
// Split-bf16 MFMA GEMM: C[B,M] = relu(A[B,K] @ W[M,K]^T + bias)
// acc += Ah*Wh + Al*Wh + Ah*Wl   (3 MFMAs, ~2^-18 relative error)
// Tile: BM=128 x BN, BK=32, 4 waves (2x2), wave tile 64 x BN/2.
// LDS: row-major 32-bf16 rows; 16B chunks XOR-swizzled chunk' = chunk^((row>>1)&3);
// global_load_lds dest linear, SOURCE pre-swizzled; ds_read applies same XOR.
template<int BN, bool SPLIT>
__global__ __launch_bounds__(256)
void mfma_gemm(const ushort_t* __restrict__ Ah, const ushort_t* __restrict__ Al,
               const ushort_t* __restrict__ Wh, const ushort_t* __restrict__ Wl,
               const float* __restrict__ bias, int K, int M,
               float* __restrict__ Cf, int ldc,
               ushort_t* __restrict__ Ch, ushort_t* __restrict__ Cl) {
    constexpr int BM = 128;
    constexpr int WN = BN / 2;
    constexpr int FN = WN / 16;
    __shared__ ushort_t AhS[BM * 32], AlS[BM * 32], WhS[BN * 32], WlS[BN * 32];

    const int tid  = threadIdx.x;
    const int lane = tid & 63;
    const int wid  = tid >> 6;
    const int wr   = wid >> 1, wc = wid & 1;
    const int row0 = blockIdx.y * BM;
    const int col0 = blockIdx.x * BN;

    // staging role per wave: 0->Ah, 1->Al, 2->Wh, 3->Wl
    const ushort_t* sbase;
    ushort_t* lbase;
    int srow0, iters;
    if (wid == 0)      { sbase = Ah; lbase = AhS; srow0 = row0; iters = BM / 16; }
    else if (wid == 1) { sbase = Al; lbase = AlS; srow0 = row0; iters = BM / 16; }
    else if (wid == 2) { sbase = Wh; lbase = WhS; srow0 = col0; iters = BN / 16; }
    else               { sbase = Wl; lbase = WlS; srow0 = col0; iters = BN / 16; }

    f32x4 acc[4][FN];
#pragma unroll
    for (int m = 0; m < 4; ++m)
#pragma unroll
        for (int n = 0; n < FN; ++n) acc[m][n] = (f32x4){0.f, 0.f, 0.f, 0.f};

    const int arow = lane & 15;
    const int kc   = lane >> 4;     // 16B chunk (8 bf16 of K) this lane consumes

    for (int k0 = 0; k0 < K; k0 += 32) {
        for (int i = 0; i < iters; ++i) {
            int slot = i * 64 + lane;
            int row  = slot >> 2, c = slot & 3;
            int cg   = c ^ ((row >> 1) & 3);          // pre-swizzled global source
            const ushort_t* g = sbase + (long)(srow0 + row) * K + k0 + cg * 8;
            GLD16(g, lbase + i * 512);
        }
        asm volatile("s_waitcnt vmcnt(0)" ::: "memory");
        __syncthreads();

        short8 ah[4], al[4];
#pragma unroll
        for (int m = 0; m < 4; ++m) {
            int r  = wr * 64 + m * 16 + arow;
            int cc = kc ^ ((r >> 1) & 3);
            ah[m] = *(const short8*)&AhS[r * 32 + cc * 8];
            al[m] = *(const short8*)&AlS[r * 32 + cc * 8];
        }
#pragma unroll
        for (int n = 0; n < FN; ++n) {
            int r  = wc * WN + n * 16 + arow;
            int cc = kc ^ ((r >> 1) & 3);
            short8 wh = *(const short8*)&WhS[r * 32 + cc * 8];
            short8 wl = *(const short8*)&WlS[r * 32 + cc * 8];
#pragma unroll
            for (int m = 0; m < 4; ++m) {
                acc[m][n] = __builtin_amdgcn_mfma_f32_16x16x32_bf16(ah[m], wh, acc[m][n], 0, 0, 0);
                acc[m][n] = __builtin_amdgcn_mfma_f32_16x16x32_bf16(al[m], wh, acc[m][n], 0, 0, 0);
                acc[m][n] = __builtin_amdgcn_mfma_f32_16x16x32_bf16(ah[m], wl, acc[m][n], 0, 0, 0);
            }
        }
        __syncthreads();
    }

    // epilogue: +bias, relu, write (C/D layout: col = lane&15, row = (lane>>4)*4 + reg)
#pragma unroll
    for (int n = 0; n < FN; ++n) {
        int gcol = col0 + wc * WN + n * 16 + (lane & 15);
        float bv = bias[gcol];
#pragma unroll
        for (int m = 0; m < 4; ++m) {
            int grow = row0 + wr * 64 + m * 16 + (lane >> 4) * 4;
#pragma unroll
            for (int r = 0; r < 4; ++r) {
                float v = fmaxf(acc[m][n][r] + bv, 0.f);
                if (SPLIT) {
                    long o = (long)(grow + r) * M + gcol;
                    ushort_t h = f2bf(v);
                    Ch[o] = h;
                    Cl[o] = f2bf(v - bf2f(h));
                } else {
                    Cf[(long)(grow + r) * ldc + gcol] = v;
                }
            }
        }
    }
}

// ---------------------------------------------------------------------------
// FUSED embedding-gather + pairwise interaction.  One block = one batch row.
// Gathers 26 embedding-row pairs straight from the tables into LDS (summed),
// plus the bottom-MLP output row xb[b]; computes the 27x27 strict-lower-tri
// dot products; writes R[b] = [x, Zflat] as split bf16 hi/lo (K padded to 416).
// Kills the former T buffer (saves ~220MB of HBM round-trip).
__global__ __launch_bounds__(256)
void gather_interact_kernel(const float* __restrict__ tables,
                            const int* __restrict__ lSi,
                            const float* __restrict__ xb,
                            ushort_t* __restrict__ Rh, ushort_t* __restrict__ Rl) {
    __shared__ float Ts[27 * 68];    // row stride 68: float4-aligned, pad 4
    const int b   = blockIdx.x;
    const int tid = threadIdx.x;

    // gather phase: slots 0..415 = (table t = s>>4, lane = s&15) summed pair;
    //               slots 416..431 = x-row float4 copy
#pragma unroll
    for (int it = 0; it < 2; ++it) {
        int s = tid + it * 256;
        if (s < 416) {
            int t = s >> 4, lane = s & 15;
            long i0 = lSi[(long)t * (2 * B_SZ) + 2 * b];
            long i1 = lSi[(long)t * (2 * B_SZ) + 2 * b + 1];
            const float4* r0 = (const float4*)(tables + ((long)t * NROWS + i0) * D_EMB);
            const float4* r1 = (const float4*)(tables + ((long)t * NROWS + i1) * D_EMB);
            float4 v0 = r0[lane], v1 = r1[lane];
            float4 sm; sm.x = v0.x + v1.x; sm.y = v0.y + v1.y;
            sm.z = v0.z + v1.z; sm.w = v0.w + v1.w;
            *(float4*)&Ts[(1 + t) * 68 + lane * 4] = sm;
        } else if (s < 432) {
            int lane = s - 416;
            float4 v = ((const float4*)(xb + (long)b * D_EMB))[lane];
            *(float4*)&Ts[lane * 4] = v;
        }
    }
    __syncthreads();

    const long rb = (long)b * 416;
    if (tid < 64) {
        float v = Ts[tid];
        ushort_t h = f2bf(v);
        Rh[rb + tid] = h;
        Rl[rb + tid] = f2bf(v - bf2f(h));
    }
    if (tid == 255) { Rh[rb + 415] = 0; Rl[rb + 415] = 0; }

    for (int p = tid; p < 351; p += 256) {
        int i = (int)((1.0f + sqrtf(1.0f + 8.0f * (float)p)) * 0.5f);
        while ((i * (i - 1)) / 2 > p) --i;
        while (((i + 1) * i) / 2 <= p) ++i;
        int j = p - (i * (i - 1)) / 2;
        const float* ri = &Ts[i * 68];
        const float* rj = &Ts[j * 68];
        float s = 0.f;
#pragma unroll
        for (int d = 0; d < 64; d += 4) {
            float4 a = *(const float4*)&ri[d];
            float4 c = *(const float4*)&rj[d];
            s = fmaf(a.x, c.x, s); s = fmaf(a.y, c.y, s);
            s = fmaf(a.z, c.z, s); s = fmaf(a.w, c.w, s);
        }
        ushort_t h = f2bf(s);
        Rh[rb + 64 + p] = h;
        Rl[rb + 64 + p] = f2bf(s - bf2f(h));
    }
}

// ---------------------------------------------------------------------------
// Final: p[b] = sigmoid(z2[b,:256] . w2 + b2). 64 lanes/row, float4 each.
__global__ __launch_bounds__(256)
void top_final_kernel(const float* __restrict__ Z, const float* __restrict__ w2,
                      const float* __restrict__ b2, float* __restrict__ out) {
    int lane = threadIdx.x & 63;
    long row = (long)blockIdx.x * 4 + (threadIdx.x >> 6);
    const float4 zv = *(const float4*)(Z + row * 256 + lane * 4);
    const float4 wv = *(const float4*)(w2 + lane * 4);
    float s = zv.x * wv.x + zv.y * wv.y + zv.z * wv.z + zv.w * wv.w;
#pragma unroll
    for (int off = 32; off; off >>= 1) s += __shfl_down(s, off);
    if (lane == 0) out[row] = 1.f / (1.f + expf(-(s + b2[0])));
}

// ---------------------------------------------------------------------------
extern "C" void kernel_launch(void* const* d_in, const int* in_sizes, int n_in,
                              void* d_out, int out_size, void* d_ws, size_t ws_size,
                              hipStream_t stream) {
    const float* dense_x = (const float*)d_in[0];
    const int*   lS_i    = (const int*)  d_in[1];
    // d_in[2] = lS_o: fixed pattern 0,2,4,.. -> not needed
    const float* tables  = (const float*)d_in[3];
    const float* bW0 = (const float*)d_in[4];   const float* bb0 = (const float*)d_in[5];
    const float* bW1 = (const float*)d_in[6];   const float* bb1 = (const float*)d_in[7];
    const float* bW2 = (const float*)d_in[8];   const float* bb2 = (const float*)d_in[9];
    const float* tW0 = (const float*)d_in[10];  const float* tb0 = (const float*)d_in[11];
    const float* tW1 = (const float*)d_in[12];  const float* tb1 = (const float*)d_in[13];
    const float* tW2 = (const float*)d_in[14];  const float* tb2 = (const float*)d_in[15];
    float* out = (float*)d_out;

    // -------- workspace layout (byte offsets, all 16B-aligned) --------
    char* w = (char*)d_ws;
    float*    xb  = (float*)   (w + 0);            // B*64*4    =  4,194,304
    ushort_t* x1h = (ushort_t*)(w + 4194304);      // B*512*2   = 16,777,216
    ushort_t* x1l = (ushort_t*)(w + 20971520);
    ushort_t* x2h = (ushort_t*)(w + 37748736);     // B*256*2   =  8,388,608
    ushort_t* x2l = (ushort_t*)(w + 46137344);
    ushort_t* Rh  = (ushort_t*)(w + 54525952);     // B*416*2   = 13,631,488
    ushort_t* Rl  = (ushort_t*)(w + 68157440);
    ushort_t* w1h = (ushort_t*)(w + 81788928);     // 256*512*2 =    262,144
    ushort_t* w1l = (ushort_t*)(w + 82051072);
    ushort_t* w2h = (ushort_t*)(w + 82313216);     // 64*256*2  =     32,768
    ushort_t* w2l = (ushort_t*)(w + 82345984);
    ushort_t* t0h = (ushort_t*)(w + 82378752);     // 512*416*2 =    425,984
    ushort_t* t0l = (ushort_t*)(w + 82804736);
    ushort_t* t1h = (ushort_t*)(w + 83230720);     // 256*512*2 =    262,144
    ushort_t* t1l = (ushort_t*)(w + 83492864);     // end = 83,755,008
    // lifetime-disjoint aliases
    ushort_t* z1h = x1h;  ushort_t* z1l = x1l;     // x1 dead after L1 GEMM
    float*    z2  = (float*)x2h;                   // x2 dead after bot2 (spans x2h+x2l)

    // 1. split weights -> bf16 hi/lo (491520 elems = 1920 blocks)
    conv_weights<<<1920, 256, 0, stream>>>(bW1, bW2, tW0, tW1,
                                           w1h, w1l, w2h, w2l, t0h, t0l, t1h, t1l);

    // 2. bottom L0: x1 = relu(dense_x @ bW0^T + bb0)   [B,512] -> hi/lo
    bot0_kernel<<<(B_SZ * 512) / 256, 256, 0, stream>>>(dense_x, bW0, bb0, x1h, x1l);

    // 3. bottom L1: x2 = relu(x1 @ bW1^T + bb1)        [B,256] -> hi/lo
    mfma_gemm<128, true><<<dim3(256 / 128, B_SZ / 128), 256, 0, stream>>>(
        x1h, x1l, w1h, w1l, bb1, 512, 256, nullptr, 0, x2h, x2l);

    // 4. bottom L2: xb = relu(x2 @ bW2^T + bb2)        [B,64] fp32, compact
    mfma_gemm<64, false><<<dim3(1, B_SZ / 128), 256, 0, stream>>>(
        x2h, x2l, w2h, w2l, bb2, 256, 64, xb, 64, nullptr, nullptr);

    // 5. fused embedding gather + interaction -> Rh/Rl [B,416]
    gather_interact_kernel<<<B_SZ, 256, 0, stream>>>(tables, lS_i, xb, Rh, Rl);

    // 6. top L0: z1 = relu(R @ tW0^T + tb0)            [B,512] -> hi/lo, K=416
    mfma_gemm<128, true><<<dim3(512 / 128, B_SZ / 128), 256, 0, stream>>>(
        Rh, Rl, t0h, t0l, tb0, 416, 512, nullptr, 0, z1h, z1l);

    // 7. top L1: z2 = relu(z1 @ tW1^T + tb1)           [B,256] fp32
    mfma_gemm<128, false><<<dim3(256 / 128, B_SZ / 128), 256, 0, stream>>>(
        z1h, z1l, t1h, t1l, tb1, 512, 256, z2, 256, nullptr, nullptr);

    // 8. final: out = sigmoid(z2 @ tW2^T + tb2)        [B,1]
    top_final_kernel<<<B_SZ / 4, 256, 0, stream>>>(z2, tW2, tb2, out);
}